// Round 10
// baseline (168.426 us; speedup 1.0000x reference)
//
#include <hip/hip_runtime.h>
#include <hip/hip_bf16.h>

#define S_LEN 4096
#define NH 16
#define HD 64
#define DIM 1024
#define NQKV 3072

typedef __attribute__((ext_vector_type(8))) short short8;
typedef __attribute__((ext_vector_type(4))) float floatx4;
typedef __attribute__((ext_vector_type(4))) float float4v;
typedef __attribute__((ext_vector_type(4))) ushort ushort4v;

static __device__ __forceinline__ ushort f32_to_bf16(float f) {
    __hip_bfloat16 b = __float2bfloat16(f);
    return *(ushort*)&b;
}

#define GLOAD_LDS16(g, l)                                                    \
    __builtin_amdgcn_global_load_lds(                                        \
        (const __attribute__((address_space(1))) void*)(g),                  \
        (__attribute__((address_space(3))) void*)(l), 16, 0, 0)

// ---------------- prep: convert x + transpose w_qkv (f32 -> bf16) ----------------
// blocks [0,2048): convert x; [2048,5120): transpose w_qkv
__global__ __launch_bounds__(256) void prep_k(const float* __restrict__ x,
                                              const float* __restrict__ wqkv,
                                              ushort* __restrict__ xb,
                                              ushort* __restrict__ wqkvT) {
    __shared__ ushort tile[32][33];
    const int b = blockIdx.x;
    if (b < 2048) {
        const size_t base = ((size_t)b * 256 + threadIdx.x) * 8;
        float4v a = *(const float4v*)(x + base);
        float4v c = *(const float4v*)(x + base + 4);
        ushort o[8];
        o[0]=f32_to_bf16(a[0]); o[1]=f32_to_bf16(a[1]); o[2]=f32_to_bf16(a[2]); o[3]=f32_to_bf16(a[3]);
        o[4]=f32_to_bf16(c[0]); o[5]=f32_to_bf16(c[1]); o[6]=f32_to_bf16(c[2]); o[7]=f32_to_bf16(c[3]);
        *(short8*)(xb + base) = *(short8*)o;
        return;
    }
    const int tb = b - 2048;
    const int bx = (tb % 96) * 32;    // col in wqkv (N)
    const int by = (tb / 96) * 32;    // row in wqkv (K)
    const int tx = threadIdx.x & 31, ty = threadIdx.x >> 5;
#pragma unroll
    for (int r = ty; r < 32; r += 8)
        tile[r][tx] = f32_to_bf16(wqkv[(size_t)(by + r) * NQKV + bx + tx]);
    __syncthreads();
#pragma unroll
    for (int r = ty; r < 32; r += 8)
        wqkvT[(size_t)(bx + r) * DIM + by + tx] = tile[tx][r];
}

// ---------------- GEMM1: qkv = x @ wqkvT^T, 128x64 tile (1536 blocks) ----------------
__global__ __launch_bounds__(256) void gemm_qkv(const ushort* __restrict__ A,
                                                const ushort* __restrict__ Bt,
                                                ushort* __restrict__ qkv,
                                                ushort* __restrict__ vt) {
    __shared__ ushort As[2][128 * 32];
    __shared__ ushort Bs[2][64 * 32];

    const int tid  = threadIdx.x;
    const int lane = tid & 63;
    const int wave = tid >> 6;
    const int wr = wave >> 1, wc = wave & 1;    // wave-tile 64x32
    const int rowBase = blockIdx.y * 128;
    const int colBase = blockIdx.x * 64;

    const int g = lane >> 4;
    const int c = lane & 15;
    const int swz = (c >> 1) & 3;

    floatx4 acc[4][2];
#pragma unroll
    for (int mi = 0; mi < 4; mi++)
#pragma unroll
        for (int ni = 0; ni < 2; ni++)
            acc[mi][ni] = (floatx4){0.f, 0.f, 0.f, 0.f};

    // A: 2 calls/wave (128 rows x 4 chunks); B: 1 call/wave (64 rows x 4 chunks)
    const ushort* aP[2];
#pragma unroll
    for (int i = 0; i < 2; i++) {
        const int s    = wave * 128 + i * 64 + lane;
        const int sRow = s >> 2;
        const int sQ   = (s & 3) ^ ((sRow >> 1) & 3);
        aP[i] = A + (size_t)(rowBase + sRow) * 1024 + sQ * 8;
    }
    const int sB    = wave * 64 + lane;
    const int sBRow = sB >> 2;
    const int sBQ   = (sB & 3) ^ ((sBRow >> 1) & 3);
    const ushort* bP = Bt + (size_t)(colBase + sBRow) * 1024 + sBQ * 8;

    auto stage = [&](int buf, int k0) {
#pragma unroll
        for (int i = 0; i < 2; i++)
            GLOAD_LDS16(aP[i] + k0, &As[buf][(wave * 2 + i) * 512]);
        GLOAD_LDS16(bP + k0, &Bs[buf][wave * 512]);
    };
    auto compute = [&](int buf) {
        short8 af[4], bfrag[2];
#pragma unroll
        for (int mi = 0; mi < 4; mi++)
            af[mi] = *(const short8*)&As[buf][((wr * 64 + mi * 16 + c) * 4 + (g ^ swz)) * 8];
#pragma unroll
        for (int ni = 0; ni < 2; ni++)
            bfrag[ni] = *(const short8*)&Bs[buf][((wc * 32 + ni * 16 + c) * 4 + (g ^ swz)) * 8];
#pragma unroll
        for (int mi = 0; mi < 4; mi++)
#pragma unroll
            for (int ni = 0; ni < 2; ni++)
                acc[mi][ni] = __builtin_amdgcn_mfma_f32_16x16x32_bf16(
                    af[mi], bfrag[ni], acc[mi][ni], 0, 0, 0);
    };

    stage(0, 0);
    for (int k0 = 0; k0 < 1024; k0 += 64) {
        __syncthreads();
        stage(1, k0 + 32);
        compute(0);
        __syncthreads();
        if (k0 + 64 < 1024) stage(0, k0 + 64);
        compute(1);
    }

    // epilogue: C/D layout col = lane&15, row = (lane>>4)*4 + r
#pragma unroll
    for (int mi = 0; mi < 4; mi++) {
#pragma unroll
        for (int ni = 0; ni < 2; ni++) {
            const int ccol  = colBase + wc * 32 + ni * 16 + c;
            const int srow0 = rowBase + wr * 64 + mi * 16 + g * 4;
            const int part = ccol >> 10;
            const int rem  = ccol & 1023;
            const int hh   = rem >> 6;
            const int dd   = rem & 63;
            if (part < 2) {
#pragma unroll
                for (int r = 0; r < 4; r++)
                    qkv[((size_t)part * NH + hh) * S_LEN * HD +
                        (size_t)(srow0 + r) * HD + dd] = f32_to_bf16(acc[mi][ni][r]);
            } else {
                ushort4v o;
#pragma unroll
                for (int r = 0; r < 4; r++) o[r] = f32_to_bf16(acc[mi][ni][r]);
                *(ushort4v*)(vt + ((size_t)hh * HD + dd) * S_LEN + srow0) = o;
            }
        }
    }
}

// ---------------- GEMM2: out = attno @ woutT^T, 64x64 tile (1024 blocks), f32 out ----------------
__global__ __launch_bounds__(256) void gemm_out(const ushort* __restrict__ A,
                                                const ushort* __restrict__ Bt,
                                                float* __restrict__ out) {
    __shared__ ushort As[2][64 * 32];
    __shared__ ushort Bs[2][64 * 32];

    const int tid  = threadIdx.x;
    const int lane = tid & 63;
    const int wave = tid >> 6;
    const int wr = wave >> 1, wc = wave & 1;    // wave-tile 32x32
    const int rowBase = blockIdx.y * 64;
    const int colBase = blockIdx.x * 64;

    const int g = lane >> 4;
    const int c = lane & 15;
    const int swz = (c >> 1) & 3;

    floatx4 acc[2][2];
#pragma unroll
    for (int mi = 0; mi < 2; mi++)
#pragma unroll
        for (int ni = 0; ni < 2; ni++)
            acc[mi][ni] = (floatx4){0.f, 0.f, 0.f, 0.f};

    const int s    = wave * 64 + lane;
    const int sRow = s >> 2;
    const int sQ   = (s & 3) ^ ((sRow >> 1) & 3);
    const ushort* aP = A  + (size_t)(rowBase + sRow) * 1024 + sQ * 8;
    const ushort* bP = Bt + (size_t)(colBase + sRow) * 1024 + sQ * 8;

    auto stage = [&](int buf, int k0) {
        GLOAD_LDS16(aP + k0, &As[buf][wave * 512]);
        GLOAD_LDS16(bP + k0, &Bs[buf][wave * 512]);
    };
    auto compute = [&](int buf) {
        short8 af[2], bfrag[2];
#pragma unroll
        for (int mi = 0; mi < 2; mi++)
            af[mi] = *(const short8*)&As[buf][((wr * 32 + mi * 16 + c) * 4 + (g ^ swz)) * 8];
#pragma unroll
        for (int ni = 0; ni < 2; ni++)
            bfrag[ni] = *(const short8*)&Bs[buf][((wc * 32 + ni * 16 + c) * 4 + (g ^ swz)) * 8];
#pragma unroll
        for (int mi = 0; mi < 2; mi++)
#pragma unroll
            for (int ni = 0; ni < 2; ni++)
                acc[mi][ni] = __builtin_amdgcn_mfma_f32_16x16x32_bf16(
                    af[mi], bfrag[ni], acc[mi][ni], 0, 0, 0);
    };

    stage(0, 0);
    for (int k0 = 0; k0 < 1024; k0 += 64) {
        __syncthreads();
        stage(1, k0 + 32);
        compute(0);
        __syncthreads();
        if (k0 + 64 < 1024) stage(0, k0 + 64);
        compute(1);
    }

#pragma unroll
    for (int mi = 0; mi < 2; mi++) {
#pragma unroll
        for (int ni = 0; ni < 2; ni++) {
            const int ccol  = colBase + wc * 32 + ni * 16 + c;
            const int srow0 = rowBase + wr * 32 + mi * 16 + g * 4;
#pragma unroll
            for (int r = 0; r < 4; r++)
                out[(size_t)(srow0 + r) * DIM + ccol] = acc[mi][ni][r];
        }
    }
}

// ---------------- attention (single barrier) + piggybacked wout transpose ----------------
// blocks [0,1024): flash attention; [1024,2048): w_out f32->bf16 transpose (ready before gemm_out)
__global__ __launch_bounds__(256) void attn_flash_k(const ushort* __restrict__ qkv,
                                                    const ushort* __restrict__ Vt,
                                                    ushort* __restrict__ attnout,
                                                    const float* __restrict__ wout,
                                                    ushort* __restrict__ woutT) {
    __shared__ ushort Kb[4][64 * 64];
    __shared__ ushort Vb[4][64 * 64];
    __shared__ ushort P[4][16 * 72];

    if (blockIdx.x >= 1024) {
        // ---- w_out transpose tile (reuse Kb as scratch) ----
        ushort (*tile)[33] = (ushort(*)[33])&Kb[0][0];
        const int tb = blockIdx.x - 1024;
        const int bx = (tb & 31) * 32;
        const int by = (tb >> 5) * 32;
        const int tx = threadIdx.x & 31, ty = threadIdx.x >> 5;
#pragma unroll
        for (int r = ty; r < 32; r += 8)
            tile[r][tx] = f32_to_bf16(wout[(size_t)(by + r) * DIM + bx + tx]);
        __syncthreads();
#pragma unroll
        for (int r = ty; r < 32; r += 8)
            woutT[(size_t)(bx + r) * DIM + by + tx] = tile[tx][r];
        return;
    }

    const int wg   = blockIdx.x;        // 0..1023
    const int h    = wg >> 6;
    const int qb   = (wg & 63) * 64;
    const int wave = threadIdx.x >> 6;
    const int lane = threadIdx.x & 63;
    const int g    = lane >> 4;
    const int c    = lane & 15;

    const ushort* Qhh = qkv + (size_t)h * S_LEN * HD;
    const ushort* Khh = qkv + (size_t)(NH + h) * S_LEN * HD;
    const ushort* Vth = Vt  + (size_t)h * HD * S_LEN;

    const int qrow0 = qb + wave * 16;

    int kbs[4], valid[4];
    kbs[0] = 0; valid[0] = 1;
#pragma unroll
    for (int ib = 1; ib < 4; ib++) {
        const int kb = qb - (3 - ib) * 64;
        valid[ib] = (kb >= 64);
        kbs[ib]   = valid[ib] ? kb : 0;
    }

    int stRow[2], stQ[2];
#pragma unroll
    for (int i = 0; i < 2; i++) {
        const int s = wave * 128 + i * 64 + lane;
        stRow[i] = s >> 3;
        stQ[i]   = (s & 7) ^ (stRow[i] & 7);
    }
#pragma unroll
    for (int ib = 0; ib < 4; ib++) {
#pragma unroll
        for (int i = 0; i < 2; i++) {
            GLOAD_LDS16(Khh + (size_t)(kbs[ib] + stRow[i]) * HD + stQ[i] * 8,
                        &Kb[ib][(wave * 2 + i) * 512]);
            GLOAD_LDS16(Vth + (size_t)stRow[i] * S_LEN + kbs[ib] + stQ[i] * 8,
                        &Vb[ib][(wave * 2 + i) * 512]);
        }
    }

    short8 qf[2];
    qf[0] = *(const short8*)(Qhh + (size_t)(qrow0 + c) * HD + g * 8);
    qf[1] = *(const short8*)(Qhh + (size_t)(qrow0 + c) * HD + 32 + g * 8);

    __syncthreads();

    const int cw = c & 7;

    floatx4 sc[4][4];
#pragma unroll
    for (int ib = 0; ib < 4; ib++)
#pragma unroll
        for (int t = 0; t < 4; t++) sc[ib][t] = (floatx4){0.f, 0.f, 0.f, 0.f};

#pragma unroll
    for (int ib = 0; ib < 4; ib++)
#pragma unroll
        for (int ks = 0; ks < 2; ks++)
#pragma unroll
            for (int t = 0; t < 4; t++) {
                short8 kf = *(const short8*)&Kb[ib][((16 * t + c) * 8 + ((ks * 4 + g) ^ cw)) * 8];
                sc[ib][t] = __builtin_amdgcn_mfma_f32_16x16x32_bf16(qf[ks], kf, sc[ib][t], 0, 0, 0);
            }

#pragma unroll
    for (int ib = 0; ib < 4; ib++)
#pragma unroll
        for (int t = 0; t < 4; t++) {
            const int j = kbs[ib] + 16 * t + c;
#pragma unroll
            for (int r = 0; r < 4; r++) {
                const int qi = qrow0 + g * 4 + r;
                const bool ok = valid[ib] && (j <= qi) && ((j >= qi - 128) || (j < 64));
                sc[ib][t][r] = ok ? sc[ib][t][r] * 0.125f : -1e30f;
            }
        }

    float lrow[4];
#pragma unroll
    for (int r = 0; r < 4; r++) {
        float mx = -1e30f;
#pragma unroll
        for (int ib = 0; ib < 4; ib++)
#pragma unroll
            for (int t = 0; t < 4; t++) mx = fmaxf(mx, sc[ib][t][r]);
#pragma unroll
        for (int msk = 1; msk < 16; msk <<= 1) mx = fmaxf(mx, __shfl_xor(mx, msk, 64));
        float psum = 0.f;
#pragma unroll
        for (int ib = 0; ib < 4; ib++)
#pragma unroll
            for (int t = 0; t < 4; t++) {
                const float p = __expf(sc[ib][t][r] - mx);
                sc[ib][t][r] = p;
                psum += p;
            }
#pragma unroll
        for (int msk = 1; msk < 16; msk <<= 1) psum += __shfl_xor(psum, msk, 64);
        lrow[r] = psum;
    }

    floatx4 Oacc[4];
#pragma unroll
    for (int nd = 0; nd < 4; nd++) Oacc[nd] = (floatx4){0.f, 0.f, 0.f, 0.f};
    ushort* pl = &P[wave][0];
#pragma unroll
    for (int ib = 0; ib < 4; ib++) {
#pragma unroll
        for (int t = 0; t < 4; t++)
#pragma unroll
            for (int r = 0; r < 4; r++)
                pl[(g * 4 + r) * 72 + t * 16 + c] = f32_to_bf16(sc[ib][t][r]);
#pragma unroll
        for (int ks = 0; ks < 2; ks++) {
            short8 pf = *(const short8*)(pl + c * 72 + ks * 32 + g * 8);
#pragma unroll
            for (int nd = 0; nd < 4; nd++) {
                short8 vf = *(const short8*)&Vb[ib][((16 * nd + c) * 8 + ((ks * 4 + g) ^ cw)) * 8];
                Oacc[nd] = __builtin_amdgcn_mfma_f32_16x16x32_bf16(pf, vf, Oacc[nd], 0, 0, 0);
            }
        }
    }

#pragma unroll
    for (int r = 0; r < 4; r++) {
        const float inv = 1.0f / lrow[r];
        const int qi = qrow0 + g * 4 + r;
#pragma unroll
        for (int nd = 0; nd < 4; nd++)
            attnout[(size_t)qi * DIM + h * HD + 16 * nd + c] = f32_to_bf16(Oacc[nd][r] * inv);
    }
}

// ---------------- launch ----------------
extern "C" void kernel_launch(void* const* d_in, const int* in_sizes, int n_in,
                              void* d_out, int out_size, void* d_ws, size_t ws_size,
                              hipStream_t stream) {
    const float* x    = (const float*)d_in[0];   // [S, DIM] f32
    const float* wqkv = (const float*)d_in[1];   // [DIM, NQKV] f32
    const float* wout = (const float*)d_in[2];   // [DIM, DIM] f32

    ushort* ws    = (ushort*)d_ws;
    ushort* xb    = ws;                                   // [S, DIM] bf16
    ushort* wqkvT = xb + (size_t)S_LEN * DIM;             // [NQKV, DIM]
    ushort* woutT = wqkvT + (size_t)NQKV * DIM;           // [DIM, DIM]
    ushort* qkv   = woutT + (size_t)DIM * DIM;            // [2][NH][S][HD] (Q,K)
    ushort* attno = qkv + (size_t)3 * NH * S_LEN * HD;    // [S, DIM]
    ushort* vt    = attno + (size_t)S_LEN * DIM;          // [NH][HD][S]

    prep_k<<<5120, 256, 0, stream>>>(x, wqkv, xb, wqkvT);

    gemm_qkv<<<dim3(NQKV / 64, S_LEN / 128), 256, 0, stream>>>(xb, wqkvT, qkv, vt);

    attn_flash_k<<<2048, 256, 0, stream>>>(qkv, vt, attno, wout, woutT);

    gemm_out<<<dim3(DIM / 64, S_LEN / 64), 256, 0, stream>>>(attno, woutT, (float*)d_out);
}

// Round 11
// 162.916 us; speedup vs baseline: 1.0338x; 1.0338x over previous
//
#include <hip/hip_runtime.h>
#include <hip/hip_bf16.h>

#define S_LEN 4096
#define NH 16
#define HD 64
#define DIM 1024
#define NQKV 3072

typedef __attribute__((ext_vector_type(8))) short short8;
typedef __attribute__((ext_vector_type(4))) float floatx4;
typedef __attribute__((ext_vector_type(4))) float float4v;
typedef __attribute__((ext_vector_type(4))) ushort ushort4v;

static __device__ __forceinline__ ushort f32_to_bf16(float f) {
    __hip_bfloat16 b = __float2bfloat16(f);
    return *(ushort*)&b;
}

#define GLOAD_LDS16(g, l)                                                    \
    __builtin_amdgcn_global_load_lds(                                        \
        (const __attribute__((address_space(1))) void*)(g),                  \
        (__attribute__((address_space(3))) void*)(l), 16, 0, 0)

#define WAITV(n) asm volatile("s_waitcnt vmcnt(" #n ")" ::: "memory")
#define RAW_BARRIER() do { __builtin_amdgcn_s_barrier(); } while (0)

// ---------------- prep: convert x + transpose w_qkv (f32 -> bf16) ----------------
__global__ __launch_bounds__(256) void prep_k(const float* __restrict__ x,
                                              const float* __restrict__ wqkv,
                                              ushort* __restrict__ xb,
                                              ushort* __restrict__ wqkvT) {
    __shared__ ushort tile[32][33];
    const int b = blockIdx.x;
    if (b < 2048) {
        const size_t base = ((size_t)b * 256 + threadIdx.x) * 8;
        float4v a = *(const float4v*)(x + base);
        float4v c = *(const float4v*)(x + base + 4);
        ushort o[8];
        o[0]=f32_to_bf16(a[0]); o[1]=f32_to_bf16(a[1]); o[2]=f32_to_bf16(a[2]); o[3]=f32_to_bf16(a[3]);
        o[4]=f32_to_bf16(c[0]); o[5]=f32_to_bf16(c[1]); o[6]=f32_to_bf16(c[2]); o[7]=f32_to_bf16(c[3]);
        *(short8*)(xb + base) = *(short8*)o;
        return;
    }
    const int tb = b - 2048;
    const int bx = (tb % 96) * 32;
    const int by = (tb / 96) * 32;
    const int tx = threadIdx.x & 31, ty = threadIdx.x >> 5;
#pragma unroll
    for (int r = ty; r < 32; r += 8)
        tile[r][tx] = f32_to_bf16(wqkv[(size_t)(by + r) * NQKV + bx + tx]);
    __syncthreads();
#pragma unroll
    for (int r = ty; r < 32; r += 8)
        wqkvT[(size_t)(bx + r) * DIM + by + tx] = tile[tx][r];
}

// ---------------- GEMM1: qkv = x @ wqkvT^T, 128x128 tile, 3-stage vmcnt pipeline ----------------
__global__ __launch_bounds__(256) void gemm_qkv(const ushort* __restrict__ A,
                                                const ushort* __restrict__ Bt,
                                                ushort* __restrict__ qkv,
                                                ushort* __restrict__ vt) {
    __shared__ ushort As[3][128 * 32];
    __shared__ ushort Bs[3][128 * 32];

    const int tid  = threadIdx.x;
    const int lane = tid & 63;
    const int wave = tid >> 6;
    const int wr = wave >> 1, wc = wave & 1;
    const int rowBase = blockIdx.y * 128;
    const int colBase = blockIdx.x * 128;

    const int g = lane >> 4;
    const int c = lane & 15;
    const int swz = (c >> 1) & 3;

    floatx4 acc[4][4];
#pragma unroll
    for (int mi = 0; mi < 4; mi++)
#pragma unroll
        for (int ni = 0; ni < 4; ni++)
            acc[mi][ni] = (floatx4){0.f, 0.f, 0.f, 0.f};

    // staging: 2 calls/wave/operand (4 loads/wave/stage)
    const ushort* aP[2];
    const ushort* bP[2];
#pragma unroll
    for (int i = 0; i < 2; i++) {
        const int s    = wave * 128 + i * 64 + lane;
        const int sRow = s >> 2;
        const int sQ   = (s & 3) ^ ((sRow >> 1) & 3);
        aP[i] = A  + (size_t)(rowBase + sRow) * 1024 + sQ * 8;
        bP[i] = Bt + (size_t)(colBase + sRow) * 1024 + sQ * 8;
    }

    auto stage = [&](int buf, int k0) {
#pragma unroll
        for (int i = 0; i < 2; i++) {
            GLOAD_LDS16(aP[i] + k0, &As[buf][(wave * 2 + i) * 512]);
            GLOAD_LDS16(bP[i] + k0, &Bs[buf][(wave * 2 + i) * 512]);
        }
    };
    auto compute = [&](int buf) {
        short8 af[4], bfrag[4];
#pragma unroll
        for (int mi = 0; mi < 4; mi++)
            af[mi] = *(const short8*)&As[buf][((wr * 64 + mi * 16 + c) * 4 + (g ^ swz)) * 8];
#pragma unroll
        for (int ni = 0; ni < 4; ni++)
            bfrag[ni] = *(const short8*)&Bs[buf][((wc * 64 + ni * 16 + c) * 4 + (g ^ swz)) * 8];
#pragma unroll
        for (int mi = 0; mi < 4; mi++)
#pragma unroll
            for (int ni = 0; ni < 4; ni++)
                acc[mi][ni] = __builtin_amdgcn_mfma_f32_16x16x32_bf16(
                    af[mi], bfrag[ni], acc[mi][ni], 0, 0, 0);
    };

    // 3-stage pipeline over 32 K-phases (BK=32). Raw barrier; never a full drain
    // until the final phase. At each barrier: own stage-i loads done (vmcnt(4)
    // leaves only stage-i+1's 4 loads in flight) => whole tile i staged.
    stage(0, 0);
    stage(1, 32);
#pragma unroll
    for (int i = 0; i < 32; i++) {
        if (i < 31) { WAITV(4); } else { WAITV(0); }
        RAW_BARRIER();
        if (i < 30) stage((i + 2) % 3, (i + 2) * 32);
        compute(i % 3);
    }

    // epilogue: C/D layout col = lane&15, row = (lane>>4)*4 + r
#pragma unroll
    for (int mi = 0; mi < 4; mi++) {
#pragma unroll
        for (int ni = 0; ni < 4; ni++) {
            const int ccol  = colBase + wc * 64 + ni * 16 + c;
            const int srow0 = rowBase + wr * 64 + mi * 16 + g * 4;
            const int part = ccol >> 10;
            const int rem  = ccol & 1023;
            const int hh   = rem >> 6;
            const int dd   = rem & 63;
            if (part < 2) {
#pragma unroll
                for (int r = 0; r < 4; r++)
                    qkv[((size_t)part * NH + hh) * S_LEN * HD +
                        (size_t)(srow0 + r) * HD + dd] = f32_to_bf16(acc[mi][ni][r]);
            } else {
                ushort4v o;
#pragma unroll
                for (int r = 0; r < 4; r++) o[r] = f32_to_bf16(acc[mi][ni][r]);
                *(ushort4v*)(vt + ((size_t)hh * HD + dd) * S_LEN + srow0) = o;
            }
        }
    }
}

// ---------------- GEMM2: out = attno @ woutT^T, 128x64 tile, 3-stage vmcnt pipeline ----------------
__global__ __launch_bounds__(256) void gemm_out(const ushort* __restrict__ A,
                                                const ushort* __restrict__ Bt,
                                                float* __restrict__ out) {
    __shared__ ushort As[3][128 * 32];
    __shared__ ushort Bs[3][64 * 32];

    const int tid  = threadIdx.x;
    const int lane = tid & 63;
    const int wave = tid >> 6;
    const int wr = wave >> 1, wc = wave & 1;    // wave-tile 64x32
    const int rowBase = blockIdx.y * 128;
    const int colBase = blockIdx.x * 64;

    const int g = lane >> 4;
    const int c = lane & 15;
    const int swz = (c >> 1) & 3;

    floatx4 acc[4][2];
#pragma unroll
    for (int mi = 0; mi < 4; mi++)
#pragma unroll
        for (int ni = 0; ni < 2; ni++)
            acc[mi][ni] = (floatx4){0.f, 0.f, 0.f, 0.f};

    // A: 2 calls/wave; B: 1 call/wave (3 loads/wave/stage)
    const ushort* aP[2];
#pragma unroll
    for (int i = 0; i < 2; i++) {
        const int s    = wave * 128 + i * 64 + lane;
        const int sRow = s >> 2;
        const int sQ   = (s & 3) ^ ((sRow >> 1) & 3);
        aP[i] = A + (size_t)(rowBase + sRow) * 1024 + sQ * 8;
    }
    const int sB    = wave * 64 + lane;
    const int sBRow = sB >> 2;
    const int sBQ   = (sB & 3) ^ ((sBRow >> 1) & 3);
    const ushort* bP = Bt + (size_t)(colBase + sBRow) * 1024 + sBQ * 8;

    auto stage = [&](int buf, int k0) {
#pragma unroll
        for (int i = 0; i < 2; i++)
            GLOAD_LDS16(aP[i] + k0, &As[buf][(wave * 2 + i) * 512]);
        GLOAD_LDS16(bP + k0, &Bs[buf][wave * 512]);
    };
    auto compute = [&](int buf) {
        short8 af[4], bfrag[2];
#pragma unroll
        for (int mi = 0; mi < 4; mi++)
            af[mi] = *(const short8*)&As[buf][((wr * 64 + mi * 16 + c) * 4 + (g ^ swz)) * 8];
#pragma unroll
        for (int ni = 0; ni < 2; ni++)
            bfrag[ni] = *(const short8*)&Bs[buf][((wc * 32 + ni * 16 + c) * 4 + (g ^ swz)) * 8];
#pragma unroll
        for (int mi = 0; mi < 4; mi++)
#pragma unroll
            for (int ni = 0; ni < 2; ni++)
                acc[mi][ni] = __builtin_amdgcn_mfma_f32_16x16x32_bf16(
                    af[mi], bfrag[ni], acc[mi][ni], 0, 0, 0);
    };

    stage(0, 0);
    stage(1, 32);
#pragma unroll
    for (int i = 0; i < 32; i++) {
        if (i < 31) { WAITV(3); } else { WAITV(0); }
        RAW_BARRIER();
        if (i < 30) stage((i + 2) % 3, (i + 2) * 32);
        compute(i % 3);
    }

#pragma unroll
    for (int mi = 0; mi < 4; mi++) {
#pragma unroll
        for (int ni = 0; ni < 2; ni++) {
            const int ccol  = colBase + wc * 32 + ni * 16 + c;
            const int srow0 = rowBase + wr * 64 + mi * 16 + g * 4;
#pragma unroll
            for (int r = 0; r < 4; r++)
                out[(size_t)(srow0 + r) * DIM + ccol] = acc[mi][ni][r];
        }
    }
}

// ---------------- attention (single barrier) + piggybacked wout transpose ----------------
__global__ __launch_bounds__(256) void attn_flash_k(const ushort* __restrict__ qkv,
                                                    const ushort* __restrict__ Vt,
                                                    ushort* __restrict__ attnout,
                                                    const float* __restrict__ wout,
                                                    ushort* __restrict__ woutT) {
    __shared__ ushort Kb[4][64 * 64];
    __shared__ ushort Vb[4][64 * 64];
    __shared__ ushort P[4][16 * 72];

    if (blockIdx.x >= 1024) {
        ushort (*tile)[33] = (ushort(*)[33])&Kb[0][0];
        const int tb = blockIdx.x - 1024;
        const int bx = (tb & 31) * 32;
        const int by = (tb >> 5) * 32;
        const int tx = threadIdx.x & 31, ty = threadIdx.x >> 5;
#pragma unroll
        for (int r = ty; r < 32; r += 8)
            tile[r][tx] = f32_to_bf16(wout[(size_t)(by + r) * DIM + bx + tx]);
        __syncthreads();
#pragma unroll
        for (int r = ty; r < 32; r += 8)
            woutT[(size_t)(bx + r) * DIM + by + tx] = tile[tx][r];
        return;
    }

    const int wg   = blockIdx.x;
    const int h    = wg >> 6;
    const int qb   = (wg & 63) * 64;
    const int wave = threadIdx.x >> 6;
    const int lane = threadIdx.x & 63;
    const int g    = lane >> 4;
    const int c    = lane & 15;

    const ushort* Qhh = qkv + (size_t)h * S_LEN * HD;
    const ushort* Khh = qkv + (size_t)(NH + h) * S_LEN * HD;
    const ushort* Vth = Vt  + (size_t)h * HD * S_LEN;

    const int qrow0 = qb + wave * 16;

    int kbs[4], valid[4];
    kbs[0] = 0; valid[0] = 1;
#pragma unroll
    for (int ib = 1; ib < 4; ib++) {
        const int kb = qb - (3 - ib) * 64;
        valid[ib] = (kb >= 64);
        kbs[ib]   = valid[ib] ? kb : 0;
    }

    int stRow[2], stQ[2];
#pragma unroll
    for (int i = 0; i < 2; i++) {
        const int s = wave * 128 + i * 64 + lane;
        stRow[i] = s >> 3;
        stQ[i]   = (s & 7) ^ (stRow[i] & 7);
    }
#pragma unroll
    for (int ib = 0; ib < 4; ib++) {
#pragma unroll
        for (int i = 0; i < 2; i++) {
            GLOAD_LDS16(Khh + (size_t)(kbs[ib] + stRow[i]) * HD + stQ[i] * 8,
                        &Kb[ib][(wave * 2 + i) * 512]);
            GLOAD_LDS16(Vth + (size_t)stRow[i] * S_LEN + kbs[ib] + stQ[i] * 8,
                        &Vb[ib][(wave * 2 + i) * 512]);
        }
    }

    short8 qf[2];
    qf[0] = *(const short8*)(Qhh + (size_t)(qrow0 + c) * HD + g * 8);
    qf[1] = *(const short8*)(Qhh + (size_t)(qrow0 + c) * HD + 32 + g * 8);

    __syncthreads();

    const int cw = c & 7;

    floatx4 sc[4][4];
#pragma unroll
    for (int ib = 0; ib < 4; ib++)
#pragma unroll
        for (int t = 0; t < 4; t++) sc[ib][t] = (floatx4){0.f, 0.f, 0.f, 0.f};

#pragma unroll
    for (int ib = 0; ib < 4; ib++)
#pragma unroll
        for (int ks = 0; ks < 2; ks++)
#pragma unroll
            for (int t = 0; t < 4; t++) {
                short8 kf = *(const short8*)&Kb[ib][((16 * t + c) * 8 + ((ks * 4 + g) ^ cw)) * 8];
                sc[ib][t] = __builtin_amdgcn_mfma_f32_16x16x32_bf16(qf[ks], kf, sc[ib][t], 0, 0, 0);
            }

#pragma unroll
    for (int ib = 0; ib < 4; ib++)
#pragma unroll
        for (int t = 0; t < 4; t++) {
            const int j = kbs[ib] + 16 * t + c;
#pragma unroll
            for (int r = 0; r < 4; r++) {
                const int qi = qrow0 + g * 4 + r;
                const bool ok = valid[ib] && (j <= qi) && ((j >= qi - 128) || (j < 64));
                sc[ib][t][r] = ok ? sc[ib][t][r] * 0.125f : -1e30f;
            }
        }

    float lrow[4];
#pragma unroll
    for (int r = 0; r < 4; r++) {
        float mx = -1e30f;
#pragma unroll
        for (int ib = 0; ib < 4; ib++)
#pragma unroll
            for (int t = 0; t < 4; t++) mx = fmaxf(mx, sc[ib][t][r]);
#pragma unroll
        for (int msk = 1; msk < 16; msk <<= 1) mx = fmaxf(mx, __shfl_xor(mx, msk, 64));
        float psum = 0.f;
#pragma unroll
        for (int ib = 0; ib < 4; ib++)
#pragma unroll
            for (int t = 0; t < 4; t++) {
                const float p = __expf(sc[ib][t][r] - mx);
                sc[ib][t][r] = p;
                psum += p;
            }
#pragma unroll
        for (int msk = 1; msk < 16; msk <<= 1) psum += __shfl_xor(psum, msk, 64);
        lrow[r] = psum;
    }

    floatx4 Oacc[4];
#pragma unroll
    for (int nd = 0; nd < 4; nd++) Oacc[nd] = (floatx4){0.f, 0.f, 0.f, 0.f};
    ushort* pl = &P[wave][0];
#pragma unroll
    for (int ib = 0; ib < 4; ib++) {
#pragma unroll
        for (int t = 0; t < 4; t++)
#pragma unroll
            for (int r = 0; r < 4; r++)
                pl[(g * 4 + r) * 72 + t * 16 + c] = f32_to_bf16(sc[ib][t][r]);
#pragma unroll
        for (int ks = 0; ks < 2; ks++) {
            short8 pf = *(const short8*)(pl + c * 72 + ks * 32 + g * 8);
#pragma unroll
            for (int nd = 0; nd < 4; nd++) {
                short8 vf = *(const short8*)&Vb[ib][((16 * nd + c) * 8 + ((ks * 4 + g) ^ cw)) * 8];
                Oacc[nd] = __builtin_amdgcn_mfma_f32_16x16x32_bf16(pf, vf, Oacc[nd], 0, 0, 0);
            }
        }
    }

#pragma unroll
    for (int r = 0; r < 4; r++) {
        const float inv = 1.0f / lrow[r];
        const int qi = qrow0 + g * 4 + r;
#pragma unroll
        for (int nd = 0; nd < 4; nd++)
            attnout[(size_t)qi * DIM + h * HD + 16 * nd + c] = f32_to_bf16(Oacc[nd][r] * inv);
    }
}

// ---------------- launch ----------------
extern "C" void kernel_launch(void* const* d_in, const int* in_sizes, int n_in,
                              void* d_out, int out_size, void* d_ws, size_t ws_size,
                              hipStream_t stream) {
    const float* x    = (const float*)d_in[0];   // [S, DIM] f32
    const float* wqkv = (const float*)d_in[1];   // [DIM, NQKV] f32
    const float* wout = (const float*)d_in[2];   // [DIM, DIM] f32

    ushort* ws    = (ushort*)d_ws;
    ushort* xb    = ws;                                   // [S, DIM] bf16
    ushort* wqkvT = xb + (size_t)S_LEN * DIM;             // [NQKV, DIM]
    ushort* woutT = wqkvT + (size_t)NQKV * DIM;           // [DIM, DIM]
    ushort* qkv   = woutT + (size_t)DIM * DIM;            // [2][NH][S][HD] (Q,K)
    ushort* attno = qkv + (size_t)3 * NH * S_LEN * HD;    // [S, DIM]
    ushort* vt    = attno + (size_t)S_LEN * DIM;          // [NH][HD][S]

    prep_k<<<5120, 256, 0, stream>>>(x, wqkv, xb, wqkvT);

    gemm_qkv<<<dim3(NQKV / 128, S_LEN / 128), 256, 0, stream>>>(xb, wqkvT, qkv, vt);

    attn_flash_k<<<2048, 256, 0, stream>>>(qkv, vt, attno, wout, woutT);

    gemm_out<<<dim3(DIM / 64, S_LEN / 128), 256, 0, stream>>>(attno, woutT, (float*)d_out);
}

// Round 12
// 159.208 us; speedup vs baseline: 1.0579x; 1.0233x over previous
//
#include <hip/hip_runtime.h>
#include <hip/hip_bf16.h>

#define S_LEN 4096
#define NH 16
#define HD 64
#define DIM 1024
#define NQKV 3072

typedef __attribute__((ext_vector_type(8))) short short8;
typedef __attribute__((ext_vector_type(4))) float floatx4;
typedef __attribute__((ext_vector_type(4))) float float4v;
typedef __attribute__((ext_vector_type(4))) ushort ushort4v;

static __device__ __forceinline__ ushort f32_to_bf16(float f) {
    __hip_bfloat16 b = __float2bfloat16(f);
    return *(ushort*)&b;
}

#define GLOAD_LDS16(g, l)                                                    \
    __builtin_amdgcn_global_load_lds(                                        \
        (const __attribute__((address_space(1))) void*)(g),                  \
        (__attribute__((address_space(3))) void*)(l), 16, 0, 0)

#define WAITV(n) asm volatile("s_waitcnt vmcnt(" #n ")" ::: "memory")
#define RAW_BARRIER() do { __builtin_amdgcn_s_barrier(); } while (0)

// ---------------- prep: convert x + transpose both weights (f32 -> bf16) ----------------
// blocks [0,2048): convert x; [2048,5120): transpose w_qkv; [5120,6144): transpose w_out
__global__ __launch_bounds__(256) void prep_k(const float* __restrict__ x,
                                              const float* __restrict__ wqkv,
                                              const float* __restrict__ wout,
                                              ushort* __restrict__ xb,
                                              ushort* __restrict__ wqkvT,
                                              ushort* __restrict__ woutT) {
    __shared__ ushort tile[32][33];
    const int b = blockIdx.x;
    if (b < 2048) {
        const size_t base = ((size_t)b * 256 + threadIdx.x) * 8;
        float4v a = *(const float4v*)(x + base);
        float4v c = *(const float4v*)(x + base + 4);
        ushort o[8];
        o[0]=f32_to_bf16(a[0]); o[1]=f32_to_bf16(a[1]); o[2]=f32_to_bf16(a[2]); o[3]=f32_to_bf16(a[3]);
        o[4]=f32_to_bf16(c[0]); o[5]=f32_to_bf16(c[1]); o[6]=f32_to_bf16(c[2]); o[7]=f32_to_bf16(c[3]);
        *(short8*)(xb + base) = *(short8*)o;
        return;
    }
    const float* src; ushort* dst; int rows, cols, bx, by;
    if (b < 5120) {
        const int tb = b - 2048;
        src = wqkv; dst = wqkvT; rows = DIM; cols = NQKV;
        bx = (tb % 96) * 32; by = (tb / 96) * 32;
    } else {
        const int tb = b - 5120;
        src = wout; dst = woutT; rows = DIM; cols = DIM;
        bx = (tb & 31) * 32; by = (tb >> 5) * 32;
    }
    const int tx = threadIdx.x & 31, ty = threadIdx.x >> 5;
#pragma unroll
    for (int r = ty; r < 32; r += 8)
        tile[r][tx] = f32_to_bf16(src[(size_t)(by + r) * cols + bx + tx]);
    __syncthreads();
#pragma unroll
    for (int r = ty; r < 32; r += 8)
        dst[(size_t)(bx + r) * rows + by + tx] = tile[tx][r];
}

// ---------------- GEMM1: qkv = x @ wqkvT^T, 128x128 tile, 3-stage vmcnt pipeline ----------------
__global__ __launch_bounds__(256) void gemm_qkv(const ushort* __restrict__ A,
                                                const ushort* __restrict__ Bt,
                                                ushort* __restrict__ qkv,
                                                ushort* __restrict__ vt) {
    __shared__ ushort As[3][128 * 32];
    __shared__ ushort Bs[3][128 * 32];

    const int tid  = threadIdx.x;
    const int lane = tid & 63;
    const int wave = tid >> 6;
    const int wr = wave >> 1, wc = wave & 1;
    const int rowBase = blockIdx.y * 128;
    const int colBase = blockIdx.x * 128;

    const int g = lane >> 4;
    const int c = lane & 15;
    const int swz = (c >> 1) & 3;

    floatx4 acc[4][4];
#pragma unroll
    for (int mi = 0; mi < 4; mi++)
#pragma unroll
        for (int ni = 0; ni < 4; ni++)
            acc[mi][ni] = (floatx4){0.f, 0.f, 0.f, 0.f};

    const ushort* aP[2];
    const ushort* bP[2];
#pragma unroll
    for (int i = 0; i < 2; i++) {
        const int s    = wave * 128 + i * 64 + lane;
        const int sRow = s >> 2;
        const int sQ   = (s & 3) ^ ((sRow >> 1) & 3);
        aP[i] = A  + (size_t)(rowBase + sRow) * 1024 + sQ * 8;
        bP[i] = Bt + (size_t)(colBase + sRow) * 1024 + sQ * 8;
    }

    auto stage = [&](int buf, int k0) {
#pragma unroll
        for (int i = 0; i < 2; i++) {
            GLOAD_LDS16(aP[i] + k0, &As[buf][(wave * 2 + i) * 512]);
            GLOAD_LDS16(bP[i] + k0, &Bs[buf][(wave * 2 + i) * 512]);
        }
    };
    auto compute = [&](int buf) {
        short8 af[4], bfrag[4];
#pragma unroll
        for (int mi = 0; mi < 4; mi++)
            af[mi] = *(const short8*)&As[buf][((wr * 64 + mi * 16 + c) * 4 + (g ^ swz)) * 8];
#pragma unroll
        for (int ni = 0; ni < 4; ni++)
            bfrag[ni] = *(const short8*)&Bs[buf][((wc * 64 + ni * 16 + c) * 4 + (g ^ swz)) * 8];
#pragma unroll
        for (int mi = 0; mi < 4; mi++)
#pragma unroll
            for (int ni = 0; ni < 4; ni++)
                acc[mi][ni] = __builtin_amdgcn_mfma_f32_16x16x32_bf16(
                    af[mi], bfrag[ni], acc[mi][ni], 0, 0, 0);
    };

    stage(0, 0);
    stage(1, 32);
#pragma unroll
    for (int i = 0; i < 32; i++) {
        if (i < 31) { WAITV(4); } else { WAITV(0); }
        RAW_BARRIER();
        if (i < 30) stage((i + 2) % 3, (i + 2) * 32);
        compute(i % 3);
    }

#pragma unroll
    for (int mi = 0; mi < 4; mi++) {
#pragma unroll
        for (int ni = 0; ni < 4; ni++) {
            const int ccol  = colBase + wc * 64 + ni * 16 + c;
            const int srow0 = rowBase + wr * 64 + mi * 16 + g * 4;
            const int part = ccol >> 10;
            const int rem  = ccol & 1023;
            const int hh   = rem >> 6;
            const int dd   = rem & 63;
            if (part < 2) {
#pragma unroll
                for (int r = 0; r < 4; r++)
                    qkv[((size_t)part * NH + hh) * S_LEN * HD +
                        (size_t)(srow0 + r) * HD + dd] = f32_to_bf16(acc[mi][ni][r]);
            } else {
                ushort4v o;
#pragma unroll
                for (int r = 0; r < 4; r++) o[r] = f32_to_bf16(acc[mi][ni][r]);
                *(ushort4v*)(vt + ((size_t)hh * HD + dd) * S_LEN + srow0) = o;
            }
        }
    }
}

// ---------------- GEMM2: out = attno @ woutT^T, 64x64 tile (1024 blocks), pipelined ----------------
__global__ __launch_bounds__(256) void gemm_out(const ushort* __restrict__ A,
                                                const ushort* __restrict__ Bt,
                                                float* __restrict__ out) {
    __shared__ ushort As[3][64 * 32];
    __shared__ ushort Bs[3][64 * 32];

    const int tid  = threadIdx.x;
    const int lane = tid & 63;
    const int wave = tid >> 6;
    const int wr = wave >> 1, wc = wave & 1;    // wave-tile 32x32
    const int rowBase = blockIdx.y * 64;
    const int colBase = blockIdx.x * 64;

    const int g = lane >> 4;
    const int c = lane & 15;
    const int swz = (c >> 1) & 3;

    floatx4 acc[2][2];
#pragma unroll
    for (int mi = 0; mi < 2; mi++)
#pragma unroll
        for (int ni = 0; ni < 2; ni++)
            acc[mi][ni] = (floatx4){0.f, 0.f, 0.f, 0.f};

    const int s    = wave * 64 + lane;
    const int sRow = s >> 2;
    const int sQ   = (s & 3) ^ ((sRow >> 1) & 3);
    const ushort* aP = A  + (size_t)(rowBase + sRow) * 1024 + sQ * 8;
    const ushort* bP = Bt + (size_t)(colBase + sRow) * 1024 + sQ * 8;

    auto stage = [&](int buf, int k0) {
        GLOAD_LDS16(aP + k0, &As[buf][wave * 512]);
        GLOAD_LDS16(bP + k0, &Bs[buf][wave * 512]);
    };
    auto compute = [&](int buf) {
        short8 af[2], bfrag[2];
#pragma unroll
        for (int mi = 0; mi < 2; mi++)
            af[mi] = *(const short8*)&As[buf][((wr * 32 + mi * 16 + c) * 4 + (g ^ swz)) * 8];
#pragma unroll
        for (int ni = 0; ni < 2; ni++)
            bfrag[ni] = *(const short8*)&Bs[buf][((wc * 32 + ni * 16 + c) * 4 + (g ^ swz)) * 8];
#pragma unroll
        for (int mi = 0; mi < 2; mi++)
#pragma unroll
            for (int ni = 0; ni < 2; ni++)
                acc[mi][ni] = __builtin_amdgcn_mfma_f32_16x16x32_bf16(
                    af[mi], bfrag[ni], acc[mi][ni], 0, 0, 0);
    };

    stage(0, 0);
    stage(1, 32);
#pragma unroll
    for (int i = 0; i < 32; i++) {
        if (i < 31) { WAITV(2); } else { WAITV(0); }
        RAW_BARRIER();
        if (i < 30) stage((i + 2) % 3, (i + 2) * 32);
        compute(i % 3);
    }

#pragma unroll
    for (int mi = 0; mi < 2; mi++) {
#pragma unroll
        for (int ni = 0; ni < 2; ni++) {
            const int ccol  = colBase + wc * 32 + ni * 16 + c;
            const int srow0 = rowBase + wr * 32 + mi * 16 + g * 4;
#pragma unroll
            for (int r = 0; r < 4; r++)
                out[(size_t)(srow0 + r) * DIM + ccol] = acc[mi][ni][r];
        }
    }
}

// ---------------- MFMA block-sparse flash attention: single barrier ----------------
__global__ __launch_bounds__(256) void attn_flash_k(const ushort* __restrict__ qkv,
                                                    const ushort* __restrict__ Vt,
                                                    ushort* __restrict__ attnout) {
    __shared__ ushort Kb[4][64 * 64];
    __shared__ ushort Vb[4][64 * 64];
    __shared__ ushort P[4][16 * 72];

    const int wg   = blockIdx.x;        // 0..1023
    const int h    = wg >> 6;
    const int qb   = (wg & 63) * 64;
    const int wave = threadIdx.x >> 6;
    const int lane = threadIdx.x & 63;
    const int g    = lane >> 4;
    const int c    = lane & 15;

    const ushort* Qhh = qkv + (size_t)h * S_LEN * HD;
    const ushort* Khh = qkv + (size_t)(NH + h) * S_LEN * HD;
    const ushort* Vth = Vt  + (size_t)h * HD * S_LEN;

    const int qrow0 = qb + wave * 16;

    int kbs[4], valid[4];
    kbs[0] = 0; valid[0] = 1;
#pragma unroll
    for (int ib = 1; ib < 4; ib++) {
        const int kb = qb - (3 - ib) * 64;
        valid[ib] = (kb >= 64);
        kbs[ib]   = valid[ib] ? kb : 0;
    }

    int stRow[2], stQ[2];
#pragma unroll
    for (int i = 0; i < 2; i++) {
        const int s = wave * 128 + i * 64 + lane;
        stRow[i] = s >> 3;
        stQ[i]   = (s & 7) ^ (stRow[i] & 7);
    }
#pragma unroll
    for (int ib = 0; ib < 4; ib++) {
#pragma unroll
        for (int i = 0; i < 2; i++) {
            GLOAD_LDS16(Khh + (size_t)(kbs[ib] + stRow[i]) * HD + stQ[i] * 8,
                        &Kb[ib][(wave * 2 + i) * 512]);
            GLOAD_LDS16(Vth + (size_t)stRow[i] * S_LEN + kbs[ib] + stQ[i] * 8,
                        &Vb[ib][(wave * 2 + i) * 512]);
        }
    }

    short8 qf[2];
    qf[0] = *(const short8*)(Qhh + (size_t)(qrow0 + c) * HD + g * 8);
    qf[1] = *(const short8*)(Qhh + (size_t)(qrow0 + c) * HD + 32 + g * 8);

    __syncthreads();

    const int cw = c & 7;

    floatx4 sc[4][4];
#pragma unroll
    for (int ib = 0; ib < 4; ib++)
#pragma unroll
        for (int t = 0; t < 4; t++) sc[ib][t] = (floatx4){0.f, 0.f, 0.f, 0.f};

#pragma unroll
    for (int ib = 0; ib < 4; ib++)
#pragma unroll
        for (int ks = 0; ks < 2; ks++)
#pragma unroll
            for (int t = 0; t < 4; t++) {
                short8 kf = *(const short8*)&Kb[ib][((16 * t + c) * 8 + ((ks * 4 + g) ^ cw)) * 8];
                sc[ib][t] = __builtin_amdgcn_mfma_f32_16x16x32_bf16(qf[ks], kf, sc[ib][t], 0, 0, 0);
            }

#pragma unroll
    for (int ib = 0; ib < 4; ib++)
#pragma unroll
        for (int t = 0; t < 4; t++) {
            const int j = kbs[ib] + 16 * t + c;
#pragma unroll
            for (int r = 0; r < 4; r++) {
                const int qi = qrow0 + g * 4 + r;
                const bool ok = valid[ib] && (j <= qi) && ((j >= qi - 128) || (j < 64));
                sc[ib][t][r] = ok ? sc[ib][t][r] * 0.125f : -1e30f;
            }
        }

    float lrow[4];
#pragma unroll
    for (int r = 0; r < 4; r++) {
        float mx = -1e30f;
#pragma unroll
        for (int ib = 0; ib < 4; ib++)
#pragma unroll
            for (int t = 0; t < 4; t++) mx = fmaxf(mx, sc[ib][t][r]);
#pragma unroll
        for (int msk = 1; msk < 16; msk <<= 1) mx = fmaxf(mx, __shfl_xor(mx, msk, 64));
        float psum = 0.f;
#pragma unroll
        for (int ib = 0; ib < 4; ib++)
#pragma unroll
            for (int t = 0; t < 4; t++) {
                const float p = __expf(sc[ib][t][r] - mx);
                sc[ib][t][r] = p;
                psum += p;
            }
#pragma unroll
        for (int msk = 1; msk < 16; msk <<= 1) psum += __shfl_xor(psum, msk, 64);
        lrow[r] = psum;
    }

    floatx4 Oacc[4];
#pragma unroll
    for (int nd = 0; nd < 4; nd++) Oacc[nd] = (floatx4){0.f, 0.f, 0.f, 0.f};
    ushort* pl = &P[wave][0];
#pragma unroll
    for (int ib = 0; ib < 4; ib++) {
#pragma unroll
        for (int t = 0; t < 4; t++)
#pragma unroll
            for (int r = 0; r < 4; r++)
                pl[(g * 4 + r) * 72 + t * 16 + c] = f32_to_bf16(sc[ib][t][r]);
#pragma unroll
        for (int ks = 0; ks < 2; ks++) {
            short8 pf = *(const short8*)(pl + c * 72 + ks * 32 + g * 8);
#pragma unroll
            for (int nd = 0; nd < 4; nd++) {
                short8 vf = *(const short8*)&Vb[ib][((16 * nd + c) * 8 + ((ks * 4 + g) ^ cw)) * 8];
                Oacc[nd] = __builtin_amdgcn_mfma_f32_16x16x32_bf16(pf, vf, Oacc[nd], 0, 0, 0);
            }
        }
    }

#pragma unroll
    for (int r = 0; r < 4; r++) {
        const float inv = 1.0f / lrow[r];
        const int qi = qrow0 + g * 4 + r;
#pragma unroll
        for (int nd = 0; nd < 4; nd++)
            attnout[(size_t)qi * DIM + h * HD + 16 * nd + c] = f32_to_bf16(Oacc[nd][r] * inv);
    }
}

// ---------------- launch ----------------
extern "C" void kernel_launch(void* const* d_in, const int* in_sizes, int n_in,
                              void* d_out, int out_size, void* d_ws, size_t ws_size,
                              hipStream_t stream) {
    const float* x    = (const float*)d_in[0];   // [S, DIM] f32
    const float* wqkv = (const float*)d_in[1];   // [DIM, NQKV] f32
    const float* wout = (const float*)d_in[2];   // [DIM, DIM] f32

    ushort* ws    = (ushort*)d_ws;
    ushort* xb    = ws;                                   // [S, DIM] bf16
    ushort* wqkvT = xb + (size_t)S_LEN * DIM;             // [NQKV, DIM]
    ushort* woutT = wqkvT + (size_t)NQKV * DIM;           // [DIM, DIM]
    ushort* qkv   = woutT + (size_t)DIM * DIM;            // [2][NH][S][HD] (Q,K)
    ushort* attno = qkv + (size_t)3 * NH * S_LEN * HD;    // [S, DIM]
    ushort* vt    = attno + (size_t)S_LEN * DIM;          // [NH][HD][S]

    prep_k<<<6144, 256, 0, stream>>>(x, wqkv, wout, xb, wqkvT, woutT);

    gemm_qkv<<<dim3(NQKV / 128, S_LEN / 128), 256, 0, stream>>>(xb, wqkvT, qkv, vt);

    attn_flash_k<<<1024, 256, 0, stream>>>(qkv, vt, attno);

    gemm_out<<<dim3(DIM / 64, S_LEN / 64), 256, 0, stream>>>(attno, woutT, (float*)d_out);
}